// Round 14
// baseline (339.805 us; speedup 1.0000x reference)
//
#include <hip/hip_runtime.h>
#include <hip/hip_bf16.h>

#define NS   48
#define NV   10
#define NEF  144
#define WN   3364
#define IND  78
#define NE   100000
#define NN   10000
#define EPS  1e-5f
#define HP   144          // hlds pitch (shorts)
#define EB   128          // edges per block (4 waves x 32)

#define A_SS 0.10206207261596575f   // 1/sqrt(96)
#define A_VS 0.22360679774997896f   // 1/sqrt(20)
#define A_SV 0.10206207261596575f
#define A_VV 0.22360679774997896f
#define RS3  0.5773502691896258f    // 1/sqrt(3)

typedef __attribute__((ext_vector_type(8)))  short    short8;
typedef __attribute__((ext_vector_type(16))) float    f32x16;
typedef __attribute__((ext_vector_type(4)))  int      int4v;
typedef __attribute__((ext_vector_type(4)))  float    float4v;
typedef __attribute__((ext_vector_type(2)))  __fp16   fp16x2;
typedef __attribute__((ext_vector_type(8)))  _Float16 half8;

#define MFMAH(a,b,c) __builtin_amdgcn_mfma_f32_32x32x16_f16((a),(b),(c),0,0,0)

// ---- workspace layout (float indices) -------------------------------------
#define TP_F    0                 // NE*IND fp16 (as shorts; 3.9 MB)
#define OFFS_F  7810160           // NN+1 ints
#define CUR_F   7820164           // NN ints
#define EL_F    7830164           // NE ints
#define PART_F  7930164           // 156*2500 floats, [feature][block]
#define RAW_F   8320164           // 156 floats (reduced stats)
#define WSBF_F  8320324           // fp16 weights region (shorts; 16B-aligned)

// fp16 weight region offsets (in shorts). FRAGMENT-MAJOR layout:
//   slice = [tile][ks][lane(64)][8shorts] -> lane*16B coalesced / LDS-stageable
#define OFF_W1  0         // 5 tiles x 9 ks x 512
#define OFF_B1  23040     // 48 slices x 9216 + bias 3072
#define OFF_B2  468480    // 10 slices x 9216 + bias 1024
#define OFF_B3  561664    // 10 slices x 4608 + bias 512
#define N_PREP  608256

__device__ __forceinline__ short toh(float v) {
    return __builtin_bit_cast(short, (_Float16)v);   // RN
}
__device__ __forceinline__ float fromh(short s) {
    return (float)__builtin_bit_cast(_Float16, s);
}
__device__ __forceinline__ unsigned pkh2(float a, float b) {
    fp16x2 h = __builtin_amdgcn_cvt_pkrtz(a, b);
    return __builtin_bit_cast(unsigned, h);
}
__device__ __forceinline__ float waveReduceSum(float v) {
    #pragma unroll
    for (int o = 32; o > 0; o >>= 1) v += __shfl_down(v, o, 64);
    return v;
}
// async global->LDS, 16B per lane; lds dest = wave-uniform base + lane*16
__device__ __forceinline__ void gl_lds16(const short* g, short* l) {
    __builtin_amdgcn_global_load_lds(
        (const __attribute__((address_space(1))) unsigned int*)g,
        (__attribute__((address_space(3))) unsigned int*)l, 16, 0, 0);
}

// ---------------------------------------------------------------------------
// Weight prep (RN): fp32 -> fp16, FRAGMENT-MAJOR; thread = one 8-short chunk
// element (tile, ks, lane, j): n = tile*32 + (lane&31), k = ks*16+(lane>>5)*8+j
// ---------------------------------------------------------------------------
__device__ __forceinline__ float prep_fetch(int idx, const float* __restrict__ fc1_w,
                                            const float* __restrict__ fc2_w,
                                            const float* __restrict__ b2)
{
    float v = 0.f;
    if (idx < OFF_B1) {                       // W1F: [tile5][ks9][lane][8]
        int r = idx;
        int tile = r / 4608, rem = r % 4608;
        int ks = rem / 512, l = (rem % 512) / 8, j = rem % 8;
        int n = tile * 32 + (l & 31);
        int k = ks * 16 + ((l >> 5) << 3) + j;
        v = (n < 144) ? fc1_w[k * 144 + n] : 0.f;
    } else if (idx < OFF_B2) {                // B1F (G1: ss cols 0-47, sv 48-57)
        int r = idx - OFF_B1;
        if (r < 442368) {
            int i = r / 9216, rem = r % 9216;
            int tile = rem / 4608; rem %= 4608;
            int ks = rem / 512, l = (rem % 512) / 8, j = rem % 8;
            int n = tile * 32 + (l & 31);
            int k = ks * 16 + ((l >> 5) << 3) + j;
            if (n < 48)      v = fc2_w[(size_t)k * WN + i * 48 + n];
            else if (n < 58) v = fc2_w[(size_t)k * WN + 2784 + i * 10 + (n - 48)];
        } else {                              // bias: K=48
            int rb = r - 442368;
            int tile = rb / 1536, rem = rb % 1536;
            int ks = rem / 512, l = (rem % 512) / 8, j = rem % 8;
            int n = tile * 32 + (l & 31);
            int k = ks * 16 + ((l >> 5) << 3) + j;
            if (n < 48)      v = b2[k * 48 + n];
            else if (n < 58) v = b2[2784 + k * 10 + (n - 48)];
        }
    } else if (idx < OFF_B3) {                // B2F (G2: vs cols 0-47)
        int r = idx - OFF_B2;
        if (r < 92160) {
            int i = r / 9216, rem = r % 9216;
            int tile = rem / 4608; rem %= 4608;
            int ks = rem / 512, l = (rem % 512) / 8, j = rem % 8;
            int n = tile * 32 + (l & 31);
            int k = ks * 16 + ((l >> 5) << 3) + j;
            if (n < 48) v = fc2_w[(size_t)k * WN + 2304 + i * 48 + n];
        } else {                              // bias: K=10 pad 16
            int rb = r - 92160;
            int tile = rb / 512, rem = rb % 512;
            int l = rem / 8, j = rem % 8;
            int n = tile * 32 + (l & 31);
            int k = ((l >> 5) << 3) + j;
            if (k < 10 && n < 48) v = b2[2304 + k * 48 + n];
        }
    } else {                                  // B3F (G3: vv cols 0-9)
        int r = idx - OFF_B3;
        if (r < 46080) {
            int i = r / 4608, rem = r % 4608;
            int ks = rem / 512, l = (rem % 512) / 8, j = rem % 8;
            int n = l & 31;
            int k = ks * 16 + ((l >> 5) << 3) + j;
            if (n < 10) v = fc2_w[(size_t)k * WN + 3264 + i * 10 + n];
        } else {                              // bias: K=10 pad 16
            int rb = r - 46080;
            int l = rb / 8, j = rb % 8;
            int n = l & 31;
            int k = ((l >> 5) << 3) + j;
            if (k < 10 && n < 10) v = b2[3264 + k * 10 + n];
        }
    }
    return v;
}

__global__ void prep_weights(const float* __restrict__ fc1_w,
                             const float* __restrict__ fc2_w,
                             const float* __restrict__ b2,
                             short* __restrict__ wsbf)
{
    int tid = blockIdx.x * 256 + threadIdx.x;
    if (tid >= N_PREP / 8) return;
    int base = tid * 8;
    short8 outv;
    #pragma unroll
    for (int j = 0; j < 8; ++j)
        outv[j] = toh(prep_fetch(base + j, fc1_w, fc2_w, b2));
    *reinterpret_cast<short8*>(wsbf + base) = outv;
}

// ---------------------------------------------------------------------------
// hist + scan fused, single block, histogram in LDS (40 KB)
// ---------------------------------------------------------------------------
__global__ __launch_bounds__(1024) void histscan_kernel(const int* __restrict__ eidx,
                                                        int* __restrict__ offs,
                                                        int* __restrict__ cursor)
{
    __shared__ int cnt[NN];       // 40 KB
    __shared__ int part[1024];
    int t = threadIdx.x;
    for (int i = t; i < NN; i += 1024) cnt[i] = 0;
    __syncthreads();
    for (int e = t; e < NE; e += 1024) atomicAdd(&cnt[eidx[e]], 1);
    __syncthreads();
    int base = t * 10;
    int local[10];
    int s = 0;
    #pragma unroll
    for (int q = 0; q < 10; ++q) {
        int i = base + q;
        int v = (i < NN) ? cnt[i] : 0;
        local[q] = s; s += v;
    }
    part[t] = s;
    __syncthreads();
    for (int o = 1; o < 1024; o <<= 1) {
        int v = (t >= o) ? part[t - o] : 0;
        __syncthreads();
        part[t] += v;
        __syncthreads();
    }
    int prev = (t == 0) ? 0 : part[t - 1];
    #pragma unroll
    for (int q = 0; q < 10; ++q) {
        int i = base + q;
        if (i < NN) { int val = prev + local[q]; offs[i] = val; cursor[i] = val; }
    }
    if (t == 1023) offs[NN] = part[1023];
}

__global__ void scatter_kernel(const int* __restrict__ eidx,
                               int* __restrict__ cursor, int* __restrict__ elist)
{
    int e = blockIdx.x * 256 + threadIdx.x;
    if (e < NE) {
        int pos = atomicAdd(&cursor[eidx[e]], 1);
        elist[pos] = e;
    }
}

// ---------------------------------------------------------------------------
// Fused MFMA kernel (fp16): 128 edges/block, 256 threads (4 waves), 2 blk/CU.
// tp written in fp16 (halves WRITE and gather read traffic).
// ---------------------------------------------------------------------------
__global__ __launch_bounds__(256, 2) void fused_main(
    const float* __restrict__ node_attr, const float* __restrict__ edge_attr,
    const float* __restrict__ edge_sh,   const float* __restrict__ b1,
    const int*   __restrict__ eidx,      const short* __restrict__ wsbf,
    short* __restrict__ tp)
{
    __shared__ short ubuf[18432];       // hlds[128][144]  UNION  stage[2][9216]
    __shared__ short xfT[96 * EB];      // transposed: [slot][edge], fp16
    __shared__ float pbuf[EB][10];      // A_SV * p per (edge, o)
    __shared__ float s0s[EB];
    __shared__ float s1s[EB][3];

    const int t    = threadIdx.x;
    const int e0   = blockIdx.x * EB;
    const int lane = t & 63, wave = t >> 6;
    const int n32  = lane & 31, kh = lane >> 5;
    const int eL   = 32 * wave + n32;          // lane's edge (local, = A-row)
    const int eLc  = min(e0 + eL, NE - 1);

    const short* W1L = wsbf + OFF_W1 + lane * 8;
    const short* B1L = wsbf + OFF_B1 + lane * 8;
    const short* B2L = wsbf + OFF_B2 + lane * 8;
    const short* B3L = wsbf + OFF_B3 + lane * 8;

    auto stageB = [&](const short* src, short* dst, int nfrag) {
        for (int f = wave; f < nfrag; f += 4)
            gl_lds16(src + f * 512 + lane * 8, dst + f * 512);
    };

    // zero xfT tail rows 88..95 (G3 bias chunk reads them vs zero-B; NaN*0=NaN)
    for (int idx = t; idx < 8 * EB; idx += 256) xfT[88 * EB + idx] = 0;

    // ---- stage edge_sh -------------------------------------------------
    if (t < EB) {
        int ee = e0 + t;
        if (ee < NE) {
            float4v sh = *reinterpret_cast<const float4v*>(edge_sh + (size_t)ee * 4);
            s0s[t] = sh.x; s1s[t][0] = sh.y; s1s[t][1] = sh.z; s1s[t][2] = sh.w;
        } else {
            s0s[t] = 0.f; s1s[t][0] = s1s[t][1] = s1s[t][2] = 0.f;
        }
    }

    // ---- node gather -> xfT (fp16) -------------------------------------
    {
        const int eg  = t & (EB - 1);
        const int jb  = t >> 7;
        const int egc = min(e0 + eg, NE - 1);
        const int dst = eidx[NE + egc];
        const float* na = node_attr + (size_t)dst * IND;
        for (int j = jb; j < IND; j += 2) {
            int slot = (j < NS) ? j : 58 + ((j - NS) % 3) * 10 + (j - NS) / 3;
            xfT[slot * EB + eg] = toh(na[j]);
        }
    }

    // ---- fc1 A-fragments straight from global (fp16 pack, 1 op/pair) ---
    half8 afc[9];
    {
        const float* ea = edge_attr + (size_t)eLc * NEF + kh * 8;
        #pragma unroll
        for (int ks = 0; ks < 9; ++ks) {
            float4v lo = *reinterpret_cast<const float4v*>(ea + ks * 16);
            float4v hi = *reinterpret_cast<const float4v*>(ea + ks * 16 + 4);
            int4v v = { (int)pkh2(lo.x, lo.y), (int)pkh2(lo.z, lo.w),
                        (int)pkh2(hi.x, hi.y), (int)pkh2(hi.z, hi.w) };
            afc[ks] = __builtin_bit_cast(half8, v);
        }
    }
    __syncthreads();

    // ---- dotv: slots 48..57 --------------------------------------------
    #pragma unroll
    for (int it = 0; it < 5; ++it) {
        int e = t & (EB - 1);
        int i = (t >> 7) + 2 * it;
        float d = fromh(xfT[(58 + i) * EB + e]) * s1s[e][0]
                + fromh(xfT[(68 + i) * EB + e]) * s1s[e][1]
                + fromh(xfT[(78 + i) * EB + e]) * s1s[e][2];
        xfT[(48 + i) * EB + e] = toh(d * RS3);
    }

    // ---- fc1: h = relu(ea @ W1 + b1) -> ubuf (fp16) --------------------
    for (int pass = 0; pass < 3; ++pass) {
        int ntA = 2 * pass, ntB = 2 * pass + 1;
        bool hasB = (pass < 2);
        f32x16 accA = 0, accB = 0;
        #pragma unroll
        for (int ks = 0; ks < 9; ++ks) {
            half8 bA = *(const half8*)(W1L + (ntA * 9 + ks) * 512);
            accA = MFMAH(afc[ks], bA, accA);
            if (hasB) {
                half8 bB = *(const half8*)(W1L + (ntB * 9 + ks) * 512);
                accB = MFMAH(afc[ks], bB, accB);
            }
        }
        int colA = ntA * 32 + n32, colB = ntB * 32 + n32;
        float b1A = (colA < NEF) ? b1[colA] : 0.f;
        float b1B = (hasB && colB < NEF) ? b1[colB] : 0.f;
        #pragma unroll
        for (int r = 0; r < 16; ++r) {
            int row = (r & 3) + 8 * (r >> 2) + 4 * kh;
            int e = 32 * wave + row;
            if (colA < NEF) ubuf[e * HP + colA] = toh(fmaxf(accA[r] + b1A, 0.f));
            if (hasB)       ubuf[e * HP + colB] = toh(fmaxf(accB[r] + b1B, 0.f));
        }
    }

    // ---- h slice to registers, PACKED (36 VGPRs; no unpack) ------------
    half8 hh[9];
    #pragma unroll
    for (int ks = 0; ks < 9; ++ks)
        hh[ks] = *(const half8*)(ubuf + eL * HP + ks * 16 + kh * 8);
    __syncthreads();   // all waves done with hlds + dotv visible -> ubuf free

    short* stg0 = ubuf;
    short* stg1 = ubuf + 9216;

    stageB(wsbf + OFF_B1, stg0, 18);
    __syncthreads();

    auto splat8 = [&](int slot) -> half8 {
        _Float16 xh = __builtin_bit_cast(_Float16, xfT[slot * EB + eL]);
        half8 r = { xh, xh, xh, xh, xh, xh, xh, xh };
        return r;
    };

    // ---- G1: ss + sv (N=64: cols 0..47 out_s-ss, 48..57 p) -------------
    f32x16 acc1a = 0, acc1b = 0, acc2a = 0, acc2b = 0;
    {
        #pragma unroll 1
        for (int i = 0; i < 48; ++i) {
            short* cur = (i & 1) ? stg1 : stg0;
            short* nxt = (i & 1) ? stg0 : stg1;
            if (i < 47) stageB(wsbf + OFF_B1 + (i + 1) * 9216, nxt, 18);
            else        stageB(wsbf + OFF_B2, nxt, 18);   // G2 chunk 0
            half8 x8 = splat8(i);
            #pragma unroll
            for (int ks = 0; ks < 9; ++ks) {
                half8 a  = hh[ks] * x8;                   // 4x v_pk_mul_f16
                half8 b0 = *(const half8*)(cur + ks * 512 + lane * 8);
                half8 b1f= *(const half8*)(cur + 4608 + ks * 512 + lane * 8);
                acc1a = MFMAH(a, b0, acc1a);
                acc1b = MFMAH(a, b1f, acc1b);
            }
            __syncthreads();
        }
        #pragma unroll
        for (int ks = 0; ks < 3; ++ks) {
            short8 a;
            #pragma unroll
            for (int j = 0; j < 8; ++j)
                a[j] = xfT[(ks * 16 + kh * 8 + j) * EB + eL];
            half8 ah = __builtin_bit_cast(half8, a);
            half8 b0 = *(const half8*)(B1L + 442368 + ks * 512);
            half8 b1f= *(const half8*)(B1L + 442368 + 1536 + ks * 512);
            acc1a = MFMAH(ah, b0, acc1a);
            acc1b = MFMAH(ah, b1f, acc1b);
        }
    }
    // ---- G2: vs (N=64, cols 0..47 add to out_s) ------------------------
    {
        #pragma unroll 1
        for (int i = 0; i < 10; ++i) {
            short* cur = (i & 1) ? stg1 : stg0;
            short* nxt = (i & 1) ? stg0 : stg1;
            if (i < 9) stageB(wsbf + OFF_B2 + (i + 1) * 9216, nxt, 18);
            else       stageB(wsbf + OFF_B3, nxt, 9);     // G3 chunk 0
            half8 x8 = splat8(48 + i);
            #pragma unroll
            for (int ks = 0; ks < 9; ++ks) {
                half8 a  = hh[ks] * x8;
                half8 b0 = *(const half8*)(cur + ks * 512 + lane * 8);
                half8 b1f= *(const half8*)(cur + 4608 + ks * 512 + lane * 8);
                acc2a = MFMAH(a, b0, acc2a);
                acc2b = MFMAH(a, b1f, acc2b);
            }
            __syncthreads();
        }
        {
            short8 a;
            #pragma unroll
            for (int j = 0; j < 8; ++j)
                a[j] = xfT[(48 + kh * 8 + j) * EB + eL];
            half8 ah = __builtin_bit_cast(half8, a);
            half8 b0 = *(const half8*)(B2L + 92160);
            half8 b1f= *(const half8*)(B2L + 92160 + 512);
            acc2a = MFMAH(ah, b0, acc2a);
            acc2b = MFMAH(ah, b1f, acc2b);
        }
    }
    // ---- scalar epilogue: fp16 stores to tp; stash p in pbuf -----------
    #pragma unroll
    for (int r = 0; r < 16; ++r) {
        int row = (r & 3) + 8 * (r >> 2) + 4 * kh;
        int e = 32 * wave + row;
        int ge = e0 + e;
        if (ge < NE) {
            float s0e = s0s[e];
            short* rowp = tp + (size_t)ge * IND;
            rowp[n32] = toh(A_SS * s0e * acc1a[r] + A_VS * acc2a[r]);
            int col = 32 + n32;
            if (col < 48) {
                rowp[col] = toh(A_SS * s0e * acc1b[r] + A_VS * acc2b[r]);
            } else if (col < 58) {
                pbuf[e][col - 48] = A_SV * acc1b[r];
            }
        }
    }
    // ---- G3: vv (N=32; B-fragment reused across the 3 components) ------
    {
        f32x16 acc30 = 0, acc31 = 0, acc32 = 0;
        #pragma unroll 1
        for (int i = 0; i < 10; ++i) {
            short* cur = (i & 1) ? stg1 : stg0;
            short* nxt = (i & 1) ? stg0 : stg1;
            if (i < 9) stageB(wsbf + OFF_B3 + (i + 1) * 4608, nxt, 9);
            half8 x0 = splat8(58 + i), x1 = splat8(68 + i), x2 = splat8(78 + i);
            #pragma unroll
            for (int ks = 0; ks < 9; ++ks) {
                half8 b0 = *(const half8*)(cur + ks * 512 + lane * 8);
                acc30 = MFMAH(hh[ks] * x0, b0, acc30);
                acc31 = MFMAH(hh[ks] * x1, b0, acc31);
                acc32 = MFMAH(hh[ks] * x2, b0, acc32);
            }
            __syncthreads();
        }
        {
            half8 bb = *(const half8*)(B3L + 46080);
            short8 a;
            #pragma unroll
            for (int j = 0; j < 8; ++j) a[j] = xfT[(58 + kh * 8 + j) * EB + eL];
            acc30 = MFMAH(__builtin_bit_cast(half8, a), bb, acc30);
            #pragma unroll
            for (int j = 0; j < 8; ++j) a[j] = xfT[(68 + kh * 8 + j) * EB + eL];
            acc31 = MFMAH(__builtin_bit_cast(half8, a), bb, acc31);
            #pragma unroll
            for (int j = 0; j < 8; ++j) a[j] = xfT[(78 + kh * 8 + j) * EB + eL];
            acc32 = MFMAH(__builtin_bit_cast(half8, a), bb, acc32);
        }
        if (n32 < 10) {
            #pragma unroll
            for (int r = 0; r < 16; ++r) {
                int row = (r & 3) + 8 * (r >> 2) + 4 * kh;
                int e = 32 * wave + row;
                int ge = e0 + e;
                if (ge < NE) {
                    float p  = pbuf[e][n32];
                    float qs = A_VV * s0s[e];
                    size_t base = (size_t)ge * IND + 48 + n32 * 3;
                    tp[base + 0] = toh(p * s1s[e][0] + qs * acc30[r]);
                    tp[base + 1] = toh(p * s1s[e][1] + qs * acc31[r]);
                    tp[base + 2] = toh(p * s1s[e][2] + qs * acc32[r]);
                }
            }
        }
    }
}

// ---------------------------------------------------------------------------
// Gather + block stat partials (fp16 tp reads); partial is [feature][block]
// ---------------------------------------------------------------------------
__global__ __launch_bounds__(256) void gather_kernel(const short* __restrict__ tp,
                                                     const int* __restrict__ offs,
                                                     const int* __restrict__ elist,
                                                     const float* __restrict__ node_attr,
                                                     float* __restrict__ out,
                                                     float* __restrict__ partial)
{
    __shared__ float sS[IND], sQ[IND];
    int t = threadIdx.x;
    if (t < IND) { sS[t] = 0.f; sQ[t] = 0.f; }
    __syncthreads();

    int node = blockIdx.x * 4 + (t >> 6);
    int lane = t & 63;
    int beg = offs[node], end = offs[node + 1];
    float a0 = 0.f, a1 = 0.f;
    for (int p = beg; p < end; ++p) {
        int e = elist[p];
        const short* row = tp + (size_t)e * IND;
        a0 += fromh(row[lane]);
        if (lane < 14) a1 += fromh(row[64 + lane]);
    }
    float c = fmaxf((float)(end - beg), 1.0f);
    size_t base = (size_t)node * IND;
    float v0 = a0 / c + node_attr[base + lane];
    out[base + lane] = v0;
    atomicAdd(&sS[lane], v0);
    atomicAdd(&sQ[lane], v0 * v0);
    if (lane < 14) {
        float v1 = a1 / c + node_attr[base + 64 + lane];
        out[base + 64 + lane] = v1;
        atomicAdd(&sS[64 + lane], v1);
        atomicAdd(&sQ[64 + lane], v1 * v1);
    }
    __syncthreads();
    if (t < IND)            partial[(size_t)t * 2500 + blockIdx.x] = sS[t];
    else if (t < 2 * IND)   partial[(size_t)(t - IND + IND) * 2500 + blockIdx.x] = sQ[t - IND];
}

// reduce partial[156][2500] -> raw[156]  (coalesced over blocks)
__global__ __launch_bounds__(256) void reduce_kernel(const float* __restrict__ partial,
                                                     float* __restrict__ raw)
{
    int f = blockIdx.x;
    float s = 0.f;
    for (int b = threadIdx.x; b < 2500; b += 256)
        s += partial[(size_t)f * 2500 + b];
    s = waveReduceSum(s);
    __shared__ float r[4];
    int w = threadIdx.x >> 6, lane = threadIdx.x & 63;
    if (lane == 0) r[w] = s;
    __syncthreads();
    if (threadIdx.x == 0) raw[f] = r[0] + r[1] + r[2] + r[3];
}

// normalize directly from raw sums (per-thread stat math, L2-cached reads)
// raw[0..77] = sum, raw[78..155] = sumsq
__global__ void normalize_kernel(const float* __restrict__ raw,
                                 const float* __restrict__ bnw,
                                 const float* __restrict__ bnb,
                                 float* __restrict__ out)
{
    int idx = blockIdx.x * 256 + threadIdx.x;
    if (idx >= NN * IND) return;
    int j = idx % IND;
    float x = out[idx];
    const float inv = 1.0f / (float)NN;
    if (j < NS) {
        float mu  = raw[j] * inv;
        float var = raw[IND + j] * inv - mu * mu;
        out[idx] = (x - mu) * rsqrtf(var + EPS) * bnw[j] + bnb[j];
    } else {
        int v = (j - NS) / 3;
        float fn = (raw[IND + NS + 3 * v] + raw[IND + NS + 3 * v + 1] +
                    raw[IND + NS + 3 * v + 2]) * (inv / 3.0f);
        out[idx] = x * bnw[NS + v] * rsqrtf(fn + EPS);
    }
}

// ---------------------------------------------------------------------------
extern "C" void kernel_launch(void* const* d_in, const int* in_sizes, int n_in,
                              void* d_out, int out_size, void* d_ws, size_t ws_size,
                              hipStream_t stream)
{
    (void)in_sizes; (void)n_in; (void)out_size; (void)ws_size;
    const float* node_attr = (const float*)d_in[0];
    const float* edge_attr = (const float*)d_in[1];
    const float* edge_sh   = (const float*)d_in[2];
    const float* fc1_w     = (const float*)d_in[3];
    const float* fc1_b     = (const float*)d_in[4];
    const float* fc2_w     = (const float*)d_in[5];
    const float* fc2_b     = (const float*)d_in[6];
    const float* bn_w      = (const float*)d_in[7];
    const float* bn_b      = (const float*)d_in[8];
    const int*   eidx      = (const int*)d_in[9];

    float* wsf   = (float*)d_ws;
    short* tp    = (short*)(wsf + TP_F);
    int*   offs  = (int*)(wsf + OFFS_F);
    int*   cur   = (int*)(wsf + CUR_F);
    int*   elist = (int*)(wsf + EL_F);
    float* part  = wsf + PART_F;
    float* raw   = wsf + RAW_F;
    short* wsbf  = (short*)(wsf + WSBF_F);
    float* out   = (float*)d_out;

    prep_weights<<<(N_PREP / 8 + 255) / 256, 256, 0, stream>>>(fc1_w, fc2_w, fc2_b, wsbf);
    histscan_kernel<<<1, 1024, 0, stream>>>(eidx, offs, cur);
    scatter_kernel<<<(NE + 255) / 256, 256, 0, stream>>>(eidx, cur, elist);
    fused_main<<<(NE + EB - 1) / EB, 256, 0, stream>>>(node_attr, edge_attr, edge_sh,
                                                       fc1_b, eidx, wsbf, tp);
    gather_kernel<<<NN / 4, 256, 0, stream>>>(tp, offs, elist, node_attr, out, part);
    reduce_kernel<<<156, 256, 0, stream>>>(part, raw);
    normalize_kernel<<<(NN * IND + 255) / 256, 256, 0, stream>>>(raw, bn_w, bn_b, out);
}

// Round 15
// 324.560 us; speedup vs baseline: 1.0470x; 1.0470x over previous
//
#include <hip/hip_runtime.h>
#include <hip/hip_bf16.h>

#define NS   48
#define NV   10
#define NEF  144
#define WN   3364
#define IND  78
#define NE   100000
#define NN   10000
#define EPS  1e-5f
#define HP   144          // hlds pitch (shorts)
#define EB   128          // edges per block (4 waves x 32)

#define A_SS 0.10206207261596575f   // 1/sqrt(96)
#define A_VS 0.22360679774997896f   // 1/sqrt(20)
#define A_SV 0.10206207261596575f
#define A_VV 0.22360679774997896f
#define RS3  0.5773502691896258f    // 1/sqrt(3)

typedef __attribute__((ext_vector_type(8)))  short    short8;
typedef __attribute__((ext_vector_type(16))) float    f32x16;
typedef __attribute__((ext_vector_type(4)))  int      int4v;
typedef __attribute__((ext_vector_type(4)))  float    float4v;
typedef __attribute__((ext_vector_type(2)))  __fp16   fp16x2;
typedef __attribute__((ext_vector_type(8)))  _Float16 half8;

#define MFMAH(a,b,c) __builtin_amdgcn_mfma_f32_32x32x16_f16((a),(b),(c),0,0,0)

// ---- workspace layout (float indices) -------------------------------------
#define TP_F    0                 // NE*IND fp16 (as shorts; CSR-ordered rows)
#define CNT_F   7800160           // NN ints
#define OFFS_F  7810160           // NN+1 ints
#define CUR_F   7820164           // NN ints
#define EPOS_F  7830164           // NE ints (edge -> CSR row position)
#define PART_F  7930164           // 156*2500 floats, [feature][block]
#define RAW_F   8320164           // 156 floats (reduced stats)
#define WSBF_F  8320324           // fp16 weights region (shorts; 16B-aligned)

// fp16 weight region offsets (in shorts). FRAGMENT-MAJOR layout:
//   slice = [tile][ks][lane(64)][8shorts] -> lane*16B coalesced / LDS-stageable
#define OFF_W1  0         // 5 tiles x 9 ks x 512
#define OFF_B1  23040     // 48 slices x 9216 + bias 3072
#define OFF_B2  468480    // 10 slices x 9216 + bias 1024
#define OFF_B3  561664    // 10 slices x 4608 + bias 512
#define N_PREP  608256

__device__ __forceinline__ short toh(float v) {
    return __builtin_bit_cast(short, (_Float16)v);   // RN
}
__device__ __forceinline__ float fromh(short s) {
    return (float)__builtin_bit_cast(_Float16, s);
}
__device__ __forceinline__ unsigned pkh2(float a, float b) {
    fp16x2 h = __builtin_amdgcn_cvt_pkrtz(a, b);
    return __builtin_bit_cast(unsigned, h);
}
__device__ __forceinline__ float waveReduceSum(float v) {
    #pragma unroll
    for (int o = 32; o > 0; o >>= 1) v += __shfl_down(v, o, 64);
    return v;
}
// async global->LDS, 16B per lane; lds dest = wave-uniform base + lane*16
__device__ __forceinline__ void gl_lds16(const short* g, short* l) {
    __builtin_amdgcn_global_load_lds(
        (const __attribute__((address_space(1))) unsigned int*)g,
        (__attribute__((address_space(3))) unsigned int*)l, 16, 0, 0);
}

// ---------------------------------------------------------------------------
// Weight prep (RN): fp32 -> fp16, FRAGMENT-MAJOR; thread = one 8-short chunk
// ---------------------------------------------------------------------------
__device__ __forceinline__ float prep_fetch(int idx, const float* __restrict__ fc1_w,
                                            const float* __restrict__ fc2_w,
                                            const float* __restrict__ b2)
{
    float v = 0.f;
    if (idx < OFF_B1) {                       // W1F: [tile5][ks9][lane][8]
        int r = idx;
        int tile = r / 4608, rem = r % 4608;
        int ks = rem / 512, l = (rem % 512) / 8, j = rem % 8;
        int n = tile * 32 + (l & 31);
        int k = ks * 16 + ((l >> 5) << 3) + j;
        v = (n < 144) ? fc1_w[k * 144 + n] : 0.f;
    } else if (idx < OFF_B2) {                // B1F (G1: ss cols 0-47, sv 48-57)
        int r = idx - OFF_B1;
        if (r < 442368) {
            int i = r / 9216, rem = r % 9216;
            int tile = rem / 4608; rem %= 4608;
            int ks = rem / 512, l = (rem % 512) / 8, j = rem % 8;
            int n = tile * 32 + (l & 31);
            int k = ks * 16 + ((l >> 5) << 3) + j;
            if (n < 48)      v = fc2_w[(size_t)k * WN + i * 48 + n];
            else if (n < 58) v = fc2_w[(size_t)k * WN + 2784 + i * 10 + (n - 48)];
        } else {                              // bias: K=48
            int rb = r - 442368;
            int tile = rb / 1536, rem = rb % 1536;
            int ks = rem / 512, l = (rem % 512) / 8, j = rem % 8;
            int n = tile * 32 + (l & 31);
            int k = ks * 16 + ((l >> 5) << 3) + j;
            if (n < 48)      v = b2[k * 48 + n];
            else if (n < 58) v = b2[2784 + k * 10 + (n - 48)];
        }
    } else if (idx < OFF_B3) {                // B2F (G2: vs cols 0-47)
        int r = idx - OFF_B2;
        if (r < 92160) {
            int i = r / 9216, rem = r % 9216;
            int tile = rem / 4608; rem %= 4608;
            int ks = rem / 512, l = (rem % 512) / 8, j = rem % 8;
            int n = tile * 32 + (l & 31);
            int k = ks * 16 + ((l >> 5) << 3) + j;
            if (n < 48) v = fc2_w[(size_t)k * WN + 2304 + i * 48 + n];
        } else {                              // bias: K=10 pad 16
            int rb = r - 92160;
            int tile = rb / 512, rem = rb % 512;
            int l = rem / 8, j = rem % 8;
            int n = tile * 32 + (l & 31);
            int k = ((l >> 5) << 3) + j;
            if (k < 10 && n < 48) v = b2[2304 + k * 48 + n];
        }
    } else {                                  // B3F (G3: vv cols 0-9)
        int r = idx - OFF_B3;
        if (r < 46080) {
            int i = r / 4608, rem = r % 4608;
            int ks = rem / 512, l = (rem % 512) / 8, j = rem % 8;
            int n = l & 31;
            int k = ks * 16 + ((l >> 5) << 3) + j;
            if (n < 10) v = fc2_w[(size_t)k * WN + 3264 + i * 10 + n];
        } else {                              // bias: K=10 pad 16
            int rb = r - 46080;
            int l = rb / 8, j = rb % 8;
            int n = l & 31;
            int k = ((l >> 5) << 3) + j;
            if (k < 10 && n < 10) v = b2[3264 + k * 10 + n];
        }
    }
    return v;
}

__global__ void prep_weights(const float* __restrict__ fc1_w,
                             const float* __restrict__ fc2_w,
                             const float* __restrict__ b2,
                             short* __restrict__ wsbf)
{
    int tid = blockIdx.x * 256 + threadIdx.x;
    if (tid >= N_PREP / 8) return;
    int base = tid * 8;
    short8 outv;
    #pragma unroll
    for (int j = 0; j < 8; ++j)
        outv[j] = toh(prep_fetch(base + j, fc1_w, fc2_w, b2));
    *reinterpret_cast<short8*>(wsbf + base) = outv;
}

// ---------------------------------------------------------------------------
// CSR build: histogram -> scan -> position scatter (epos[e], no elist)
// ---------------------------------------------------------------------------
__global__ void hist_kernel(const int* __restrict__ eidx, int* __restrict__ cntI)
{
    int e = blockIdx.x * 256 + threadIdx.x;
    if (e < NE) atomicAdd(&cntI[eidx[e]], 1);
}

__global__ __launch_bounds__(1024) void scan_kernel(const int* __restrict__ cntI,
                                                    int* __restrict__ offs,
                                                    int* __restrict__ cursor)
{
    __shared__ int part[1024];
    int t = threadIdx.x;
    int base = t * 10;
    int local[10];
    int s = 0;
    #pragma unroll
    for (int q = 0; q < 10; ++q) {
        int i = base + q;
        int v = (i < NN) ? cntI[i] : 0;
        local[q] = s; s += v;
    }
    part[t] = s;
    __syncthreads();
    for (int o = 1; o < 1024; o <<= 1) {
        int v = (t >= o) ? part[t - o] : 0;
        __syncthreads();
        part[t] += v;
        __syncthreads();
    }
    int prev = (t == 0) ? 0 : part[t - 1];
    #pragma unroll
    for (int q = 0; q < 10; ++q) {
        int i = base + q;
        if (i < NN) { int val = prev + local[q]; offs[i] = val; cursor[i] = val; }
    }
    if (t == 1023) offs[NN] = part[1023];
}

__global__ void scatter_kernel(const int* __restrict__ eidx,
                               int* __restrict__ cursor, int* __restrict__ epos)
{
    int e = blockIdx.x * 256 + threadIdx.x;
    if (e < NE) epos[e] = atomicAdd(&cursor[eidx[e]], 1);
}

// ---------------------------------------------------------------------------
// Fused MFMA kernel (fp16): 128 edges/block, 256 threads (4 waves), 2 blk/CU.
// tp rows written at CSR position epos[e] -> gather reads are sequential.
// ---------------------------------------------------------------------------
__global__ __launch_bounds__(256, 2) void fused_main(
    const float* __restrict__ node_attr, const float* __restrict__ edge_attr,
    const float* __restrict__ edge_sh,   const float* __restrict__ b1,
    const int*   __restrict__ eidx,      const int* __restrict__ epos,
    const short* __restrict__ wsbf,      short* __restrict__ tp)
{
    __shared__ short ubuf[18432];       // hlds[128][144]  UNION  stage[2][9216]
    __shared__ short xfT[96 * EB];      // transposed: [slot][edge], fp16
    __shared__ float pbuf[EB][10];      // A_SV * p per (edge, o)
    __shared__ float s0s[EB];
    __shared__ float s1s[EB][3];
    __shared__ int   eposs[EB];

    const int t    = threadIdx.x;
    const int e0   = blockIdx.x * EB;
    const int lane = t & 63, wave = t >> 6;
    const int n32  = lane & 31, kh = lane >> 5;
    const int eL   = 32 * wave + n32;          // lane's edge (local, = A-row)
    const int eLc  = min(e0 + eL, NE - 1);

    const short* W1L = wsbf + OFF_W1 + lane * 8;
    const short* B1L = wsbf + OFF_B1 + lane * 8;
    const short* B2L = wsbf + OFF_B2 + lane * 8;
    const short* B3L = wsbf + OFF_B3 + lane * 8;

    auto stageB = [&](const short* src, short* dst, int nfrag) {
        for (int f = wave; f < nfrag; f += 4)
            gl_lds16(src + f * 512 + lane * 8, dst + f * 512);
    };

    // zero xfT tail rows 88..95 (G3 bias chunk reads them vs zero-B; NaN*0=NaN)
    for (int idx = t; idx < 8 * EB; idx += 256) xfT[88 * EB + idx] = 0;

    // ---- stage edge_sh + epos ------------------------------------------
    if (t < EB) {
        int ee = e0 + t;
        if (ee < NE) {
            float4v sh = *reinterpret_cast<const float4v*>(edge_sh + (size_t)ee * 4);
            s0s[t] = sh.x; s1s[t][0] = sh.y; s1s[t][1] = sh.z; s1s[t][2] = sh.w;
            eposs[t] = epos[ee];
        } else {
            s0s[t] = 0.f; s1s[t][0] = s1s[t][1] = s1s[t][2] = 0.f;
            eposs[t] = 0;
        }
    }

    // ---- node gather -> xfT (fp16) -------------------------------------
    {
        const int eg  = t & (EB - 1);
        const int jb  = t >> 7;
        const int egc = min(e0 + eg, NE - 1);
        const int dst = eidx[NE + egc];
        const float* na = node_attr + (size_t)dst * IND;
        for (int j = jb; j < IND; j += 2) {
            int slot = (j < NS) ? j : 58 + ((j - NS) % 3) * 10 + (j - NS) / 3;
            xfT[slot * EB + eg] = toh(na[j]);
        }
    }

    // ---- fc1 A-fragments straight from global (fp16 pack, 1 op/pair) ---
    half8 afc[9];
    {
        const float* ea = edge_attr + (size_t)eLc * NEF + kh * 8;
        #pragma unroll
        for (int ks = 0; ks < 9; ++ks) {
            float4v lo = *reinterpret_cast<const float4v*>(ea + ks * 16);
            float4v hi = *reinterpret_cast<const float4v*>(ea + ks * 16 + 4);
            int4v v = { (int)pkh2(lo.x, lo.y), (int)pkh2(lo.z, lo.w),
                        (int)pkh2(hi.x, hi.y), (int)pkh2(hi.z, hi.w) };
            afc[ks] = __builtin_bit_cast(half8, v);
        }
    }
    __syncthreads();

    // ---- dotv: slots 48..57 --------------------------------------------
    #pragma unroll
    for (int it = 0; it < 5; ++it) {
        int e = t & (EB - 1);
        int i = (t >> 7) + 2 * it;
        float d = fromh(xfT[(58 + i) * EB + e]) * s1s[e][0]
                + fromh(xfT[(68 + i) * EB + e]) * s1s[e][1]
                + fromh(xfT[(78 + i) * EB + e]) * s1s[e][2];
        xfT[(48 + i) * EB + e] = toh(d * RS3);
    }

    // ---- fc1: h = relu(ea @ W1 + b1) -> ubuf (fp16) --------------------
    for (int pass = 0; pass < 3; ++pass) {
        int ntA = 2 * pass, ntB = 2 * pass + 1;
        bool hasB = (pass < 2);
        f32x16 accA = 0, accB = 0;
        #pragma unroll
        for (int ks = 0; ks < 9; ++ks) {
            half8 bA = *(const half8*)(W1L + (ntA * 9 + ks) * 512);
            accA = MFMAH(afc[ks], bA, accA);
            if (hasB) {
                half8 bB = *(const half8*)(W1L + (ntB * 9 + ks) * 512);
                accB = MFMAH(afc[ks], bB, accB);
            }
        }
        int colA = ntA * 32 + n32, colB = ntB * 32 + n32;
        float b1A = (colA < NEF) ? b1[colA] : 0.f;
        float b1B = (hasB && colB < NEF) ? b1[colB] : 0.f;
        #pragma unroll
        for (int r = 0; r < 16; ++r) {
            int row = (r & 3) + 8 * (r >> 2) + 4 * kh;
            int e = 32 * wave + row;
            if (colA < NEF) ubuf[e * HP + colA] = toh(fmaxf(accA[r] + b1A, 0.f));
            if (hasB)       ubuf[e * HP + colB] = toh(fmaxf(accB[r] + b1B, 0.f));
        }
    }

    // ---- h slice to registers, PACKED (36 VGPRs; no unpack) ------------
    half8 hh[9];
    #pragma unroll
    for (int ks = 0; ks < 9; ++ks)
        hh[ks] = *(const half8*)(ubuf + eL * HP + ks * 16 + kh * 8);
    __syncthreads();   // all waves done with hlds + dotv visible -> ubuf free

    short* stg0 = ubuf;
    short* stg1 = ubuf + 9216;

    stageB(wsbf + OFF_B1, stg0, 18);
    __syncthreads();

    auto splat8 = [&](int slot) -> half8 {
        _Float16 xh = __builtin_bit_cast(_Float16, xfT[slot * EB + eL]);
        half8 r = { xh, xh, xh, xh, xh, xh, xh, xh };
        return r;
    };

    // ---- G1: ss + sv (N=64: cols 0..47 out_s-ss, 48..57 p) -------------
    f32x16 acc1a = 0, acc1b = 0, acc2a = 0, acc2b = 0;
    {
        #pragma unroll 1
        for (int i = 0; i < 48; ++i) {
            short* cur = (i & 1) ? stg1 : stg0;
            short* nxt = (i & 1) ? stg0 : stg1;
            if (i < 47) stageB(wsbf + OFF_B1 + (i + 1) * 9216, nxt, 18);
            else        stageB(wsbf + OFF_B2, nxt, 18);   // G2 chunk 0
            half8 x8 = splat8(i);
            #pragma unroll
            for (int ks = 0; ks < 9; ++ks) {
                half8 a  = hh[ks] * x8;                   // 4x v_pk_mul_f16
                half8 b0 = *(const half8*)(cur + ks * 512 + lane * 8);
                half8 b1f= *(const half8*)(cur + 4608 + ks * 512 + lane * 8);
                acc1a = MFMAH(a, b0, acc1a);
                acc1b = MFMAH(a, b1f, acc1b);
            }
            __syncthreads();
        }
        #pragma unroll
        for (int ks = 0; ks < 3; ++ks) {
            short8 a;
            #pragma unroll
            for (int j = 0; j < 8; ++j)
                a[j] = xfT[(ks * 16 + kh * 8 + j) * EB + eL];
            half8 ah = __builtin_bit_cast(half8, a);
            half8 b0 = *(const half8*)(B1L + 442368 + ks * 512);
            half8 b1f= *(const half8*)(B1L + 442368 + 1536 + ks * 512);
            acc1a = MFMAH(ah, b0, acc1a);
            acc1b = MFMAH(ah, b1f, acc1b);
        }
    }
    // ---- G2: vs (N=64, cols 0..47 add to out_s) ------------------------
    {
        #pragma unroll 1
        for (int i = 0; i < 10; ++i) {
            short* cur = (i & 1) ? stg1 : stg0;
            short* nxt = (i & 1) ? stg0 : stg1;
            if (i < 9) stageB(wsbf + OFF_B2 + (i + 1) * 9216, nxt, 18);
            else       stageB(wsbf + OFF_B3, nxt, 9);     // G3 chunk 0
            half8 x8 = splat8(48 + i);
            #pragma unroll
            for (int ks = 0; ks < 9; ++ks) {
                half8 a  = hh[ks] * x8;
                half8 b0 = *(const half8*)(cur + ks * 512 + lane * 8);
                half8 b1f= *(const half8*)(cur + 4608 + ks * 512 + lane * 8);
                acc2a = MFMAH(a, b0, acc2a);
                acc2b = MFMAH(a, b1f, acc2b);
            }
            __syncthreads();
        }
        {
            short8 a;
            #pragma unroll
            for (int j = 0; j < 8; ++j)
                a[j] = xfT[(48 + kh * 8 + j) * EB + eL];
            half8 ah = __builtin_bit_cast(half8, a);
            half8 b0 = *(const half8*)(B2L + 92160);
            half8 b1f= *(const half8*)(B2L + 92160 + 512);
            acc2a = MFMAH(ah, b0, acc2a);
            acc2b = MFMAH(ah, b1f, acc2b);
        }
    }
    // ---- scalar epilogue: fp16 stores to CSR-ordered tp; p in pbuf -----
    #pragma unroll
    for (int r = 0; r < 16; ++r) {
        int row = (r & 3) + 8 * (r >> 2) + 4 * kh;
        int e = 32 * wave + row;
        int ge = e0 + e;
        if (ge < NE) {
            float s0e = s0s[e];
            short* rowp = tp + (size_t)eposs[e] * IND;
            rowp[n32] = toh(A_SS * s0e * acc1a[r] + A_VS * acc2a[r]);
            int col = 32 + n32;
            if (col < 48) {
                rowp[col] = toh(A_SS * s0e * acc1b[r] + A_VS * acc2b[r]);
            } else if (col < 58) {
                pbuf[e][col - 48] = A_SV * acc1b[r];
            }
        }
    }
    // ---- G3: vv (N=32; B-fragment reused across the 3 components) ------
    {
        f32x16 acc30 = 0, acc31 = 0, acc32 = 0;
        #pragma unroll 1
        for (int i = 0; i < 10; ++i) {
            short* cur = (i & 1) ? stg1 : stg0;
            short* nxt = (i & 1) ? stg0 : stg1;
            if (i < 9) stageB(wsbf + OFF_B3 + (i + 1) * 4608, nxt, 9);
            half8 x0 = splat8(58 + i), x1 = splat8(68 + i), x2 = splat8(78 + i);
            #pragma unroll
            for (int ks = 0; ks < 9; ++ks) {
                half8 b0 = *(const half8*)(cur + ks * 512 + lane * 8);
                acc30 = MFMAH(hh[ks] * x0, b0, acc30);
                acc31 = MFMAH(hh[ks] * x1, b0, acc31);
                acc32 = MFMAH(hh[ks] * x2, b0, acc32);
            }
            __syncthreads();
        }
        {
            half8 bb = *(const half8*)(B3L + 46080);
            short8 a;
            #pragma unroll
            for (int j = 0; j < 8; ++j) a[j] = xfT[(58 + kh * 8 + j) * EB + eL];
            acc30 = MFMAH(__builtin_bit_cast(half8, a), bb, acc30);
            #pragma unroll
            for (int j = 0; j < 8; ++j) a[j] = xfT[(68 + kh * 8 + j) * EB + eL];
            acc31 = MFMAH(__builtin_bit_cast(half8, a), bb, acc31);
            #pragma unroll
            for (int j = 0; j < 8; ++j) a[j] = xfT[(78 + kh * 8 + j) * EB + eL];
            acc32 = MFMAH(__builtin_bit_cast(half8, a), bb, acc32);
        }
        if (n32 < 10) {
            #pragma unroll
            for (int r = 0; r < 16; ++r) {
                int row = (r & 3) + 8 * (r >> 2) + 4 * kh;
                int e = 32 * wave + row;
                int ge = e0 + e;
                if (ge < NE) {
                    float p  = pbuf[e][n32];
                    float qs = A_VV * s0s[e];
                    size_t base = (size_t)eposs[e] * IND + 48 + n32 * 3;
                    tp[base + 0] = toh(p * s1s[e][0] + qs * acc30[r]);
                    tp[base + 1] = toh(p * s1s[e][1] + qs * acc31[r]);
                    tp[base + 2] = toh(p * s1s[e][2] + qs * acc32[r]);
                }
            }
        }
    }
}

// ---------------------------------------------------------------------------
// Gather (sequential CSR rows, no elist) + block stat partials
// ---------------------------------------------------------------------------
__global__ __launch_bounds__(256) void gather_kernel(const short* __restrict__ tp,
                                                     const int* __restrict__ offs,
                                                     const float* __restrict__ node_attr,
                                                     float* __restrict__ out,
                                                     float* __restrict__ partial)
{
    __shared__ float sS[IND], sQ[IND];
    int t = threadIdx.x;
    if (t < IND) { sS[t] = 0.f; sQ[t] = 0.f; }
    __syncthreads();

    int node = blockIdx.x * 4 + (t >> 6);
    int lane = t & 63;
    int beg = offs[node], end = offs[node + 1];
    float a0 = 0.f, a1 = 0.f;
    for (int p = beg; p < end; ++p) {
        const short* row = tp + (size_t)p * IND;
        a0 += fromh(row[lane]);
        if (lane < 14) a1 += fromh(row[64 + lane]);
    }
    float c = fmaxf((float)(end - beg), 1.0f);
    size_t base = (size_t)node * IND;
    float v0 = a0 / c + node_attr[base + lane];
    out[base + lane] = v0;
    atomicAdd(&sS[lane], v0);
    atomicAdd(&sQ[lane], v0 * v0);
    if (lane < 14) {
        float v1 = a1 / c + node_attr[base + 64 + lane];
        out[base + 64 + lane] = v1;
        atomicAdd(&sS[64 + lane], v1);
        atomicAdd(&sQ[64 + lane], v1 * v1);
    }
    __syncthreads();
    if (t < IND)            partial[(size_t)t * 2500 + blockIdx.x] = sS[t];
    else if (t < 2 * IND)   partial[(size_t)(t) * 2500 + blockIdx.x] = sQ[t - IND];
}

// reduce partial[156][2500] -> raw[156]  (coalesced over blocks)
__global__ __launch_bounds__(256) void reduce_kernel(const float* __restrict__ partial,
                                                     float* __restrict__ raw)
{
    int f = blockIdx.x;
    float s = 0.f;
    for (int b = threadIdx.x; b < 2500; b += 256)
        s += partial[(size_t)f * 2500 + b];
    s = waveReduceSum(s);
    __shared__ float r[4];
    int w = threadIdx.x >> 6, lane = threadIdx.x & 63;
    if (lane == 0) r[w] = s;
    __syncthreads();
    if (threadIdx.x == 0) raw[f] = r[0] + r[1] + r[2] + r[3];
}

// normalize from raw sums: raw[0..77]=sum, raw[78..155]=sumsq
__global__ void normalize_kernel(const float* __restrict__ raw,
                                 const float* __restrict__ bnw,
                                 const float* __restrict__ bnb,
                                 float* __restrict__ out)
{
    int idx = blockIdx.x * 256 + threadIdx.x;
    if (idx >= NN * IND) return;
    int j = idx % IND;
    float x = out[idx];
    const float inv = 1.0f / (float)NN;
    if (j < NS) {
        float mu  = raw[j] * inv;
        float var = raw[IND + j] * inv - mu * mu;
        out[idx] = (x - mu) * rsqrtf(var + EPS) * bnw[j] + bnb[j];
    } else {
        int v = (j - NS) / 3;
        float fn = (raw[IND + NS + 3 * v] + raw[IND + NS + 3 * v + 1] +
                    raw[IND + NS + 3 * v + 2]) * (inv / 3.0f);
        out[idx] = x * bnw[NS + v] * rsqrtf(fn + EPS);
    }
}

// ---------------------------------------------------------------------------
extern "C" void kernel_launch(void* const* d_in, const int* in_sizes, int n_in,
                              void* d_out, int out_size, void* d_ws, size_t ws_size,
                              hipStream_t stream)
{
    (void)in_sizes; (void)n_in; (void)out_size; (void)ws_size;
    const float* node_attr = (const float*)d_in[0];
    const float* edge_attr = (const float*)d_in[1];
    const float* edge_sh   = (const float*)d_in[2];
    const float* fc1_w     = (const float*)d_in[3];
    const float* fc1_b     = (const float*)d_in[4];
    const float* fc2_w     = (const float*)d_in[5];
    const float* fc2_b     = (const float*)d_in[6];
    const float* bn_w      = (const float*)d_in[7];
    const float* bn_b      = (const float*)d_in[8];
    const int*   eidx      = (const int*)d_in[9];

    float* wsf   = (float*)d_ws;
    short* tp    = (short*)(wsf + TP_F);
    int*   cntI  = (int*)(wsf + CNT_F);
    int*   offs  = (int*)(wsf + OFFS_F);
    int*   cur   = (int*)(wsf + CUR_F);
    int*   epos  = (int*)(wsf + EPOS_F);
    float* part  = wsf + PART_F;
    float* raw   = wsf + RAW_F;
    short* wsbf  = (short*)(wsf + WSBF_F);
    float* out   = (float*)d_out;

    (void)hipMemsetAsync(cntI, 0, NN * sizeof(int), stream);
    prep_weights<<<(N_PREP / 8 + 255) / 256, 256, 0, stream>>>(fc1_w, fc2_w, fc2_b, wsbf);
    hist_kernel<<<(NE + 255) / 256, 256, 0, stream>>>(eidx, cntI);
    scan_kernel<<<1, 1024, 0, stream>>>(cntI, offs, cur);
    scatter_kernel<<<(NE + 255) / 256, 256, 0, stream>>>(eidx, cur, epos);
    fused_main<<<(NE + EB - 1) / EB, 256, 0, stream>>>(node_attr, edge_attr, edge_sh,
                                                       fc1_b, eidx, epos, wsbf, tp);
    gather_kernel<<<NN / 4, 256, 0, stream>>>(tp, offs, node_attr, out, part);
    reduce_kernel<<<156, 256, 0, stream>>>(part, raw);
    normalize_kernel<<<(NN * IND + 255) / 256, 256, 0, stream>>>(raw, bn_w, bn_b, out);
}